// Round 3
// baseline (231.730 us; speedup 1.0000x reference)
//
#include <hip/hip_runtime.h>

// De-emphasis IIR: y[n] = x[n] + C*y[n-1] per row, 64 rows of 480000 fp32.
//
// R7 (post-mortem of R4/R5/R6): three structurally different kernels (LDS
// block w/ barriers; DMA double-buffer w/ counted vmcnt; barrier-free
// independent waves) ALL land at 75-78 us, ~2.5 TB/s, VALU <10%, conflicts 0.
// A structure-invariant limiter => shared per-CU pipes not in our counters:
// the DS pipe (shfl = ds_bpermute, a 64-lane crossbar op) and the L1/TA
// vector-memory pipe. Per-CU accounting: R6 paid 8 bpermute per 256-elem
// pass (540 wave-passes/CU) -> tens of us of DS occupancy; VALUBusy never
// sees it. R7 is the discriminating experiment: amortize the wave scan.
//
//   SEG=16 elems/lane (4x float4), SPAN=1024/pass: 4x fewer shfl per byte.
//   VMEM instrs per byte unchanged (already max width dwordx4).
//   1-wave blocks: 59 waves/row x 64 rows = 3776 blocks, 14.75/CU, ~2%
//   imbalance, no dead waves, no barriers, no LDS.
//   PF=2-pass register prefetch ring (8 KB/wave in flight = 4x R6 coverage).
//   Per pass: 15-fma serial local scan, 6-shfl lane-constant affine scan
//   (A = C^16 lane-invariant per step), 1 fma cross-pass carry chain.
//
// Cross-wave carry: 1024-elem halo (1 full pass); 0.97^1024 ~ 3e-14.
// (512-halo validated R1-R6 at absmax 0.0625 = fp32 association noise;
// 1024 is strictly tighter. Threshold 0.4475.)

#define COEFF 0.97f
#define ROW_LEN 480000
#define SEG 16                              // elems per lane per pass
#define CPT (SEG / 4)                       // 4 float4 per lane per pass
#define SPAN_W (64 * SEG)                   // 1024 elems per wave-pass
#define P_HALO 1
#define P_OUT 8
#define P_TOT (P_OUT + P_HALO)              // 9
#define OUT_W (P_OUT * SPAN_W)              // 8192 output elems per wave
#define WPR ((ROW_LEN + OUT_W - 1) / OUT_W) // 59 waves per row
#define PF 2                                // prefetch depth in passes

typedef float v4f __attribute__((ext_vector_type(4)));

constexpr float fpow(float b, int n) {
    float r = 1.0f;
    for (int i = 0; i < n; ++i) r *= b;
    return r;
}
// wave-scan step factors: C^(SEG * 2^k)
constexpr float S0 = fpow(COEFF, SEG * 1);    // C^16
constexpr float S1 = fpow(COEFF, SEG * 2);    // C^32
constexpr float S2 = fpow(COEFF, SEG * 4);    // C^64
constexpr float S3 = fpow(COEFF, SEG * 8);    // C^128
constexpr float S4 = fpow(COEFF, SEG * 16);   // C^256
constexpr float S5 = fpow(COEFF, SEG * 32);   // C^512
constexpr float CP = fpow(COEFF, SPAN_W);     // C^1024 per-pass carry decay

struct Pows { float p[SEG + 1]; };
constexpr Pows make_pows() {
    Pows P{};
    float r = 1.0f;
    for (int i = 0; i <= SEG; ++i) { P.p[i] = r; r *= COEFF; }
    return P;
}
constexpr Pows PW = make_pows();   // PW.p[i] = COEFF^i

__global__ __launch_bounds__(64, 4) void deemph_kernel(const float* __restrict__ x,
                                                       float* __restrict__ y) {
    const int lane = threadIdx.x;            // 64-thread block = 1 wave
    const int widx = blockIdx.x;             // wave index within row
    const int row  = blockIdx.y;

    const float* __restrict__ xrow = x + (long long)row * ROW_LEN;
    float* __restrict__ yrow       = y + (long long)row * ROW_LEN;

    // element base of this lane for pass 0 (pass 0 = halo, may be <0)
    const int lbase = widx * OUT_W - P_HALO * SPAN_W + SEG * lane;

    // Aex = C^(SEG*lane): exact bit-product, loop-invariant
    float Aex = 1.0f;
    if (lane & 1)  Aex *= S0;
    if (lane & 2)  Aex *= S1;
    if (lane & 4)  Aex *= S2;
    if (lane & 8)  Aex *= S3;
    if (lane & 16) Aex *= S4;
    if (lane & 32) Aex *= S5;

    // ---- prefetch ring: PF passes resident in registers ----
    v4f rb[PF][CPT];
    #pragma unroll
    for (int q = 0; q < PF; ++q) {
        #pragma unroll
        for (int cc = 0; cc < CPT; ++cc) {
            const int e = lbase + q * SPAN_W + 4 * cc;
            v4f v = {0.0f, 0.0f, 0.0f, 0.0f};
            if (e >= 0 && e < ROW_LEN) v = *(const v4f*)(xrow + e);
            rb[q][cc] = v;
        }
    }

    float c = 0.0f;   // carry: y just before the current pass
    #pragma unroll
    for (int p = 0; p < P_TOT; ++p) {
        // consume pass p from the ring
        float l[SEG];
        #pragma unroll
        for (int cc = 0; cc < CPT; ++cc) {
            v4f v = rb[p % PF][cc];          // static after full unroll
            l[4*cc+0] = v.x; l[4*cc+1] = v.y; l[4*cc+2] = v.z; l[4*cc+3] = v.w;
        }
        // refill the slot with pass p+PF
        if (p + PF < P_TOT) {
            #pragma unroll
            for (int cc = 0; cc < CPT; ++cc) {
                const int e = lbase + (p + PF) * SPAN_W + 4 * cc;
                v4f v = {0.0f, 0.0f, 0.0f, 0.0f};
                if (e >= 0 && e < ROW_LEN) v = *(const v4f*)(xrow + e);
                rb[p % PF][cc] = v;
            }
        }

        // local inclusive scan, zero carry-in (carry folded at the end)
        #pragma unroll
        for (int i = 1; i < SEG; ++i) l[i] = fmaf(COEFF, l[i-1], l[i]);

        // wave inclusive scan on segment sums (A lane-constant per step)
        float Bv = l[SEG-1], Bp;
        Bp = __shfl_up(Bv, 1);  if (lane >= 1)  Bv = fmaf(S0, Bp, Bv);
        Bp = __shfl_up(Bv, 2);  if (lane >= 2)  Bv = fmaf(S1, Bp, Bv);
        Bp = __shfl_up(Bv, 4);  if (lane >= 4)  Bv = fmaf(S2, Bp, Bv);
        Bp = __shfl_up(Bv, 8);  if (lane >= 8)  Bv = fmaf(S3, Bp, Bv);
        Bp = __shfl_up(Bv, 16); if (lane >= 16) Bv = fmaf(S4, Bp, Bv);
        Bp = __shfl_up(Bv, 32); if (lane >= 32) Bv = fmaf(S5, Bp, Bv);
        float Bex = __shfl_up(Bv, 1);
        if (lane == 0) Bex = 0.0f;
        const float B63 = __shfl(Bv, 63);    // raw whole-pass contribution

        const float Kt = fmaf(c, Aex, Bex);  // y just before this lane's seg
        c = fmaf(c, CP, B63);                // 1-fma cross-pass chain

        if (p >= P_HALO) {
            #pragma unroll
            for (int cc = 0; cc < CPT; ++cc) {
                const int e = lbase + p * SPAN_W + 4 * cc;
                if (e < ROW_LEN) {           // e >= 0 guaranteed for p>=1
                    v4f o;
                    o.x = fmaf(Kt, PW.p[4*cc+1], l[4*cc+0]);
                    o.y = fmaf(Kt, PW.p[4*cc+2], l[4*cc+1]);
                    o.z = fmaf(Kt, PW.p[4*cc+3], l[4*cc+2]);
                    o.w = fmaf(Kt, PW.p[4*cc+4], l[4*cc+3]);
                    *(v4f*)(yrow + e) = o;
                }
            }
        }
    }
}

extern "C" void kernel_launch(void* const* d_in, const int* in_sizes, int n_in,
                              void* d_out, int out_size, void* d_ws, size_t ws_size,
                              hipStream_t stream) {
    (void)n_in; (void)d_ws; (void)ws_size; (void)out_size;
    const float* x = (const float*)d_in[0];
    float* y = (float*)d_out;
    const int n_rows = in_sizes[0] / ROW_LEN;  // 64 for (32,2,480000)
    dim3 grid(WPR, n_rows);
    deemph_kernel<<<grid, 64, 0, stream>>>(x, y);
}

// Round 4
// 230.471 us; speedup vs baseline: 1.0055x; 1.0055x over previous
//
#include <hip/hip_runtime.h>

// De-emphasis IIR: y[n] = x[n] + C*y[n-1] per row, 64 rows of 480000 fp32.
//
// R8 (post-mortem of R7): R7 bundled TWO changes -- 4x fewer shfl/byte
// (SEG 4->16) AND 1-wave workgroups -- and occupancy collapsed 62->28%
// (single-wave workgroups don't fill the CU at this grid size), regressing
// to 90 us. Confounded experiment. R8 keeps R7's inner loop byte-for-byte
// and restores the 4-wave workgroup packaging (waves fully independent:
// no barriers, no LDS, they only share a workgroup slot):
//
//   SEG=16 elems/lane (4x float4), SPAN=1024/wave-pass, 6-shfl affine scan
//   per pass (A = C^16 lane-invariant per step -> B-only scan, constexpr
//   factors), 15-fma serial local scan, 1-fma cross-pass carry chain.
//   P_OUT=5 output passes + 1 halo pass per wave (OUT_W=5120):
//     94 waves/row -> 24 blocks/row x 64 rows = 1536 blocks
//     -> 6 blocks/CU -> 24 waves/CU (~75% occupancy vs R7's 28%).
//   PF=2 register prefetch ring (4 KB/wave outstanding).
//
// Discriminator at matched occupancy vs R6 (8 shfl per 256 elems, 76.6 us):
//   ~55-62 us  -> DS-pipe (shfl) theory confirmed, push SEG wider.
//   ~76 us     -> shfl exonerated; plateau = practical mixed R/W ceiling;
//                 next: store-path (nontemporal) experiments.
//
// Cross-wave carry: 1024-elem halo (1 full pass); 0.97^1024 ~ 3e-14.
// (512-halo validated R1-R6 at absmax 0.0625 = fp32 association noise.)

#define COEFF 0.97f
#define ROW_LEN 480000
#define SEG 16                              // elems per lane per pass
#define CPT (SEG / 4)                       // 4 float4 per lane per pass
#define SPAN_W (64 * SEG)                   // 1024 elems per wave-pass
#define P_HALO 1
#define P_OUT 5
#define P_TOT (P_OUT + P_HALO)              // 6
#define OUT_W (P_OUT * SPAN_W)              // 5120 output elems per wave
#define WPR ((ROW_LEN + OUT_W - 1) / OUT_W) // 94 waves per row
#define BLOCK 256
#define WAVES (BLOCK / 64)                  // 4 independent waves per block
#define PF 2                                // prefetch depth in passes

typedef float v4f __attribute__((ext_vector_type(4)));

constexpr float fpow(float b, int n) {
    float r = 1.0f;
    for (int i = 0; i < n; ++i) r *= b;
    return r;
}
// wave-scan step factors: C^(SEG * 2^k)
constexpr float S0 = fpow(COEFF, SEG * 1);    // C^16
constexpr float S1 = fpow(COEFF, SEG * 2);    // C^32
constexpr float S2 = fpow(COEFF, SEG * 4);    // C^64
constexpr float S3 = fpow(COEFF, SEG * 8);    // C^128
constexpr float S4 = fpow(COEFF, SEG * 16);   // C^256
constexpr float S5 = fpow(COEFF, SEG * 32);   // C^512
constexpr float CP = fpow(COEFF, SPAN_W);     // C^1024 per-pass carry decay

struct Pows { float p[SEG + 1]; };
constexpr Pows make_pows() {
    Pows P{};
    float r = 1.0f;
    for (int i = 0; i <= SEG; ++i) { P.p[i] = r; r *= COEFF; }
    return P;
}
constexpr Pows PW = make_pows();   // PW.p[i] = COEFF^i

__global__ __launch_bounds__(BLOCK, 6) void deemph_kernel(const float* __restrict__ x,
                                                          float* __restrict__ y) {
    const int lane = threadIdx.x & 63;
    const int wave = threadIdx.x >> 6;
    const int widx = blockIdx.x * WAVES + wave;   // wave index within row
    if (widx >= WPR) return;   // wave-uniform; no barriers anywhere
    const int row  = blockIdx.y;

    const float* __restrict__ xrow = x + (long long)row * ROW_LEN;
    float* __restrict__ yrow       = y + (long long)row * ROW_LEN;

    // element base of this lane for pass 0 (pass 0 = halo, may be <0)
    const int lbase = widx * OUT_W - P_HALO * SPAN_W + SEG * lane;

    // Aex = C^(SEG*lane): exact bit-product, loop-invariant
    float Aex = 1.0f;
    if (lane & 1)  Aex *= S0;
    if (lane & 2)  Aex *= S1;
    if (lane & 4)  Aex *= S2;
    if (lane & 8)  Aex *= S3;
    if (lane & 16) Aex *= S4;
    if (lane & 32) Aex *= S5;

    // ---- prefetch ring: PF passes resident in registers ----
    v4f rb[PF][CPT];
    #pragma unroll
    for (int q = 0; q < PF; ++q) {
        #pragma unroll
        for (int cc = 0; cc < CPT; ++cc) {
            const int e = lbase + q * SPAN_W + 4 * cc;
            v4f v = {0.0f, 0.0f, 0.0f, 0.0f};
            if (e >= 0 && e < ROW_LEN) v = *(const v4f*)(xrow + e);
            rb[q][cc] = v;
        }
    }

    float c = 0.0f;   // carry: y just before the current pass
    #pragma unroll
    for (int p = 0; p < P_TOT; ++p) {
        // consume pass p from the ring
        float l[SEG];
        #pragma unroll
        for (int cc = 0; cc < CPT; ++cc) {
            v4f v = rb[p % PF][cc];          // static after full unroll
            l[4*cc+0] = v.x; l[4*cc+1] = v.y; l[4*cc+2] = v.z; l[4*cc+3] = v.w;
        }
        // refill the slot with pass p+PF
        if (p + PF < P_TOT) {
            #pragma unroll
            for (int cc = 0; cc < CPT; ++cc) {
                const int e = lbase + (p + PF) * SPAN_W + 4 * cc;
                v4f v = {0.0f, 0.0f, 0.0f, 0.0f};
                if (e >= 0 && e < ROW_LEN) v = *(const v4f*)(xrow + e);
                rb[p % PF][cc] = v;
            }
        }

        // local inclusive scan, zero carry-in (carry folded at the end)
        #pragma unroll
        for (int i = 1; i < SEG; ++i) l[i] = fmaf(COEFF, l[i-1], l[i]);

        // wave inclusive scan on segment sums (A lane-constant per step)
        float Bv = l[SEG-1], Bp;
        Bp = __shfl_up(Bv, 1);  if (lane >= 1)  Bv = fmaf(S0, Bp, Bv);
        Bp = __shfl_up(Bv, 2);  if (lane >= 2)  Bv = fmaf(S1, Bp, Bv);
        Bp = __shfl_up(Bv, 4);  if (lane >= 4)  Bv = fmaf(S2, Bp, Bv);
        Bp = __shfl_up(Bv, 8);  if (lane >= 8)  Bv = fmaf(S3, Bp, Bv);
        Bp = __shfl_up(Bv, 16); if (lane >= 16) Bv = fmaf(S4, Bp, Bv);
        Bp = __shfl_up(Bv, 32); if (lane >= 32) Bv = fmaf(S5, Bp, Bv);
        float Bex = __shfl_up(Bv, 1);
        if (lane == 0) Bex = 0.0f;
        const float B63 = __shfl(Bv, 63);    // raw whole-pass contribution

        const float Kt = fmaf(c, Aex, Bex);  // y just before this lane's seg
        c = fmaf(c, CP, B63);                // 1-fma cross-pass chain

        if (p >= P_HALO) {
            #pragma unroll
            for (int cc = 0; cc < CPT; ++cc) {
                const int e = lbase + p * SPAN_W + 4 * cc;
                if (e < ROW_LEN) {           // e >= 0 guaranteed for p>=1
                    v4f o;
                    o.x = fmaf(Kt, PW.p[4*cc+1], l[4*cc+0]);
                    o.y = fmaf(Kt, PW.p[4*cc+2], l[4*cc+1]);
                    o.z = fmaf(Kt, PW.p[4*cc+3], l[4*cc+2]);
                    o.w = fmaf(Kt, PW.p[4*cc+4], l[4*cc+3]);
                    *(v4f*)(yrow + e) = o;
                }
            }
        }
    }
}

extern "C" void kernel_launch(void* const* d_in, const int* in_sizes, int n_in,
                              void* d_out, int out_size, void* d_ws, size_t ws_size,
                              hipStream_t stream) {
    (void)n_in; (void)d_ws; (void)ws_size; (void)out_size;
    const float* x = (const float*)d_in[0];
    float* y = (float*)d_out;
    const int n_rows = in_sizes[0] / ROW_LEN;  // 64 for (32,2,480000)
    dim3 grid((WPR + WAVES - 1) / WAVES, n_rows);
    deemph_kernel<<<grid, BLOCK, 0, stream>>>(x, y);
}

// Round 5
// 218.383 us; speedup vs baseline: 1.0611x; 1.0554x over previous
//
#include <hip/hip_runtime.h>

// De-emphasis IIR: y[n] = x[n] + C*y[n-1] per row, 64 rows of 480000 fp32.
//
// R9 (post-mortem of R4-R8): five structures, occupancy 28-65%, all pinned
// at 2.3-2.9 TB/s CU-side traffic; VALU<10%, conflicts 0, HBM idle (fill
// hits 6.5 TB/s). Shfl-amortization (R8) REGRESSED -> DS-pipe theory dead.
// Only surviving model: queue/latency equilibrium -- each wave holds just
// PF*1KB in flight, loaded latency inflates to outstanding/BW, per-wave
// throughput pinned ~0.5 GB/s, aggregate = waves * 0.5. Levers never yet
// pulled: (1) MLP depth, (2) real read latency. R9 pulls both:
//
//   - SEG=4 (best inner loop, R6), PF=8 ring -> 8KB/wave outstanding
//     (vs 3KB in R6), ~5x chip-wide outstanding bytes.
//   - exact-fill grid: OUT_W=3840 (15 out passes + 2 halo), WPR=125
//     (125*3840 = 480000 exactly), 32 blocks/row x 64 = 2048 blocks =
//     exactly 8 blocks/CU; __launch_bounds__(256,8) caps VGPR<=64 ->
//     up to 32 waves/CU resident.
//   - NON-TEMPORAL full-line stores: y no longer write-allocates in L3.
//     x (123MB) then fits L3 across bench invocations (current FETCH=67-77MB
//     of 123 ideal shows y is thrashing x out; x+y=245MB ~ L3 size).
//     Reads drop to L3 latency -> serial pass waits shrink. (R3's nt
//     disaster was partial-line scatter; these are full 64B-line waves.)
//
// Cross-wave carry: 512-elem halo (2 passes); 0.97^512 ~ 1.7e-7 (validated
// R1-R8: absmax 0.0625 = fp32 association noise, threshold 0.4475).
// All load/store predicates wave-uniform (SPAN_W=256 divides everything).

#define COEFF 0.97f
#define ROW_LEN 480000
#define SEG 4
#define SPAN_W 256                          // elems per wave-pass (64*4)
#define HALO 512
#define P_HALO 2
#define P_OUT 15
#define P_TOT (P_OUT + P_HALO)              // 17
#define OUT_W (P_OUT * SPAN_W)              // 3840; 125*3840 = 480000 exact
#define WPR (ROW_LEN / OUT_W)               // 125 waves per row
#define BLOCK 256
#define WAVES (BLOCK / 64)                  // 4 independent waves per block
#define PF 8                                // prefetch ring depth (passes)

typedef float v4f __attribute__((ext_vector_type(4)));

constexpr float fpow(float b, int n) {
    float r = 1.0f;
    for (int i = 0; i < n; ++i) r *= b;
    return r;
}
// wave-scan step factors: C^(SEG * 2^k)
constexpr float S0 = fpow(COEFF, 4);
constexpr float S1 = fpow(COEFF, 8);
constexpr float S2 = fpow(COEFF, 16);
constexpr float S3 = fpow(COEFF, 32);
constexpr float S4 = fpow(COEFF, 64);
constexpr float S5 = fpow(COEFF, 128);
constexpr float CP = fpow(COEFF, SPAN_W);   // C^256 per-pass carry decay
constexpr float C1P = fpow(COEFF, 1);
constexpr float C2P = fpow(COEFF, 2);
constexpr float C3P = fpow(COEFF, 3);
constexpr float C4P = fpow(COEFF, 4);

__global__ __launch_bounds__(BLOCK, 8) void deemph_kernel(const float* __restrict__ x,
                                                          float* __restrict__ y) {
    const int lane = threadIdx.x & 63;
    const int wave = threadIdx.x >> 6;
    const int widx = blockIdx.x * WAVES + wave;   // wave index within row
    if (widx >= WPR) return;   // wave-uniform; no barriers anywhere
    const int row  = blockIdx.y;

    const float* __restrict__ xrow = x + (long long)row * ROW_LEN;
    float* __restrict__ yrow       = y + (long long)row * ROW_LEN;

    // lane's element base for pass 0 (passes 0,1 = halo; may be <0 at widx 0)
    const int lbase = widx * OUT_W - HALO + 4 * lane;

    // Aex = C^(4*lane): exact bit-product, loop-invariant
    float Aex = 1.0f;
    if (lane & 1)  Aex *= S0;
    if (lane & 2)  Aex *= S1;
    if (lane & 4)  Aex *= S2;
    if (lane & 8)  Aex *= S3;
    if (lane & 16) Aex *= S4;
    if (lane & 32) Aex *= S5;

    // ---- deep prefetch ring: PF=8 passes (8 KB/wave) in flight ----
    v4f rb[PF];
    #pragma unroll
    for (int q = 0; q < PF; ++q) {
        const int e = lbase + q * SPAN_W;
        v4f v = {0.0f, 0.0f, 0.0f, 0.0f};
        if (e >= 0 && e < ROW_LEN) v = *(const v4f*)(xrow + e);
        rb[q] = v;
    }

    float c = 0.0f;   // carry: y just before the current pass
    #pragma unroll
    for (int p = 0; p < P_TOT; ++p) {
        v4f v = rb[p % PF];                  // static index after full unroll
        if (p + PF < P_TOT) {
            const int e2 = lbase + (p + PF) * SPAN_W;
            v4f nv = {0.0f, 0.0f, 0.0f, 0.0f};
            if (e2 >= 0 && e2 < ROW_LEN) nv = *(const v4f*)(xrow + e2);
            rb[p % PF] = nv;
        }

        // local inclusive scan (zero carry-in; carry folded at the end)
        const float l0 = v.x;
        const float l1 = fmaf(COEFF, l0, v.y);
        const float l2 = fmaf(COEFF, l1, v.z);
        const float l3 = fmaf(COEFF, l2, v.w);

        // wave inclusive scan on segment sums (A lane-constant per step)
        float Bv = l3, Bp;
        Bp = __shfl_up(Bv, 1);  if (lane >= 1)  Bv = fmaf(S0, Bp, Bv);
        Bp = __shfl_up(Bv, 2);  if (lane >= 2)  Bv = fmaf(S1, Bp, Bv);
        Bp = __shfl_up(Bv, 4);  if (lane >= 4)  Bv = fmaf(S2, Bp, Bv);
        Bp = __shfl_up(Bv, 8);  if (lane >= 8)  Bv = fmaf(S3, Bp, Bv);
        Bp = __shfl_up(Bv, 16); if (lane >= 16) Bv = fmaf(S4, Bp, Bv);
        Bp = __shfl_up(Bv, 32); if (lane >= 32) Bv = fmaf(S5, Bp, Bv);
        float Bex = __shfl_up(Bv, 1);
        if (lane == 0) Bex = 0.0f;
        const float B63 = __shfl(Bv, 63);    // raw whole-pass contribution

        const float Kt = fmaf(c, Aex, Bex);  // y just before this lane's seg
        c = fmaf(c, CP, B63);                // 1-fma cross-pass chain

        if (p >= P_HALO) {
            const int e = lbase + p * SPAN_W;
            if (e < ROW_LEN) {               // e >= 0 guaranteed for p>=2
                v4f o;
                o.x = fmaf(Kt, C1P, l0);
                o.y = fmaf(Kt, C2P, l1);
                o.z = fmaf(Kt, C3P, l2);
                o.w = fmaf(Kt, C4P, l3);
                __builtin_nontemporal_store(o, (v4f*)(yrow + e));
            }
        }
    }
}

extern "C" void kernel_launch(void* const* d_in, const int* in_sizes, int n_in,
                              void* d_out, int out_size, void* d_ws, size_t ws_size,
                              hipStream_t stream) {
    (void)n_in; (void)d_ws; (void)ws_size; (void)out_size;
    const float* x = (const float*)d_in[0];
    float* y = (float*)d_out;
    const int n_rows = in_sizes[0] / ROW_LEN;  // 64 for (32,2,480000)
    dim3 grid((WPR + WAVES - 1) / WAVES, n_rows);   // 32 x 64 = 2048 blocks
    deemph_kernel<<<grid, BLOCK, 0, stream>>>(x, y);
}